// Round 1
// baseline (6826.880 us; speedup 1.0000x reference)
//
#include <hip/hip_runtime.h>
#include <hip/hip_bf16.h>

// WeightedGNN forward, MI355X. Round 1: correctness-first fp32, multi-launch.
// B=16, L=64, D=256, NRELS=8. 64 sequential recurrence steps.
// ws layout: lengths(64B pad 1KB) | shift 1MB | scale 1MB | projx 1MB | h_buf 1MB | P 8MB

#define DD 256
#define LLEN 64
#define BBAT 16
#define NROWS 1024   // B*L

// ---------------- setup: lengths[b] = count(tokens[:,b] != 0) ----------------
__global__ void k_setup(const int* __restrict__ tokens, int* __restrict__ lengths) {
    int b = threadIdx.x;
    if (b < BBAT) {
        int c = 0;
        for (int l = 0; l < LLEN; ++l) c += (tokens[l * BBAT + b] != 0) ? 1 : 0;
        lengths[b] = c;
    }
}

// ---------------- in_proj: gather emb + [1024x256]@[256x768] -----------------
__global__ __launch_bounds__(256) void k_inproj(
    const int* __restrict__ tokens, const float* __restrict__ emb,
    const float* __restrict__ W_in, const float* __restrict__ b_in,
    float* __restrict__ shiftb, float* __restrict__ scaleb, float* __restrict__ projx)
{
    __shared__ float xs[8][DD];
    const int t = threadIdx.x;
    const int row0 = blockIdx.x * 8;
    for (int r = 0; r < 8; ++r) {
        int row = row0 + r;
        int b = row >> 6, l = row & 63;
        int tok = tokens[l * BBAT + b];
        xs[r][t] = emb[(long)tok * DD + t];   // pad row 0 is zeros in the table
    }
    __syncthreads();
    float a0[8], a1[8], a2[8];
#pragma unroll
    for (int r = 0; r < 8; ++r) { a0[r] = a1[r] = a2[r] = 0.f; }
    for (int k = 0; k < DD; ++k) {
        float w0 = W_in[k * 768 + t];
        float w1 = W_in[k * 768 + 256 + t];
        float w2 = W_in[k * 768 + 512 + t];
#pragma unroll
        for (int r = 0; r < 8; ++r) {
            float x = xs[r][k];
            a0[r] = fmaf(x, w0, a0[r]);
            a1[r] = fmaf(x, w1, a1[r]);
            a2[r] = fmaf(x, w2, a2[r]);
        }
    }
    float bi0 = b_in[t], bi1 = b_in[256 + t], bi2 = b_in[512 + t];
#pragma unroll
    for (int r = 0; r < 8; ++r) {
        int row = row0 + r;
        shiftb[row * DD + t] = a0[r] + bi0;
        scaleb[row * DD + t] = a1[r] + bi1;
        projx [row * DD + t] = a2[r] + bi2;
    }
}

// ------- per-iter: P = LN_perchunk(h @ W_proj + b_proj), P:[1024][8][256] -----
// grid (8 h-chunks, 32 rowgroups of 32) -> lin%8 = chunk -> W-slice stays in one XCD L2
__global__ __launch_bounds__(256) void k_proj(
    const float* __restrict__ h_in,   // [1024][256]
    const float* __restrict__ Wp,     // [256][2048]
    const float* __restrict__ bp,     // [2048]
    float* __restrict__ P)            // [1024][2048] as [row][h*256+d]
{
    __shared__ float hs[32][DD];            // 32 KB
    __shared__ float partials[4][32][2];    // wave partials: sum, sumsq
    const int t = threadIdx.x;
    const int hh = blockIdx.x;
    const int row0 = blockIdx.y * 32;
    // stage 32 h rows
    {
        const float4* src = (const float4*)(h_in + row0 * DD);
        float4* dst = (float4*)(&hs[0][0]);
        for (int e = t; e < 32 * DD / 4; e += 256) dst[e] = src[e];
    }
    __syncthreads();
    float acc[32];
#pragma unroll
    for (int r = 0; r < 32; ++r) acc[r] = 0.f;
    const int n = hh * 256 + t;
    for (int k4 = 0; k4 < DD / 4; ++k4) {
        const int k = k4 * 4;
        float w0 = Wp[(k + 0) * 2048 + n];
        float w1 = Wp[(k + 1) * 2048 + n];
        float w2 = Wp[(k + 2) * 2048 + n];
        float w3 = Wp[(k + 3) * 2048 + n];
#pragma unroll
        for (int r = 0; r < 32; ++r) {
            const float4 hv = *(const float4*)(&hs[r][k]);
            acc[r] = fmaf(hv.x, w0, acc[r]);
            acc[r] = fmaf(hv.y, w1, acc[r]);
            acc[r] = fmaf(hv.z, w2, acc[r]);
            acc[r] = fmaf(hv.w, w3, acc[r]);
        }
    }
    const float bias = bp[n];
#pragma unroll
    for (int r = 0; r < 32; ++r) acc[r] += bias;
    // LayerNorm over the 256 cols of this chunk (across the 256 threads), per row
    const int wave = t >> 6, lane = t & 63;
    for (int r = 0; r < 32; ++r) {
        float s = acc[r], ss = acc[r] * acc[r];
#pragma unroll
        for (int m = 32; m >= 1; m >>= 1) { s += __shfl_xor(s, m); ss += __shfl_xor(ss, m); }
        if (lane == 0) { partials[wave][r][0] = s; partials[wave][r][1] = ss; }
    }
    __syncthreads();
    for (int r = 0; r < 32; ++r) {
        float s  = partials[0][r][0] + partials[1][r][0] + partials[2][r][0] + partials[3][r][0];
        float ss = partials[0][r][1] + partials[1][r][1] + partials[2][r][1] + partials[3][r][1];
        float mean = s * (1.f / 256.f);
        float var  = ss * (1.f / 256.f) - mean * mean;
        float rstd = rsqrtf(var + 1e-5f);
        P[(row0 + r) * 2048 + n] = (acc[r] - mean) * rstd;
    }
}

// ------- per-iter: lin_sum -> shrink -> LN -> gate -> W_out -> tanh -> mask ---
// grid (16 b, 16 jgroups of 4) -> lin%8 = b%8 -> P[b] stays XCD-local
__global__ __launch_bounds__(256) void k_agg(
    const float* __restrict__ A,       // [16][64][64][8]  (b, i, j, h)
    const float* __restrict__ P,       // [1024][2048]  row=b*64+i, col=h*256+d
    const float* __restrict__ projx,
    const float* __restrict__ shiftb,
    const float* __restrict__ scaleb,
    const float* __restrict__ Wout,    // [256][256]
    const float* __restrict__ bout,    // [256]
    const int* __restrict__ lengths,
    float* __restrict__ h_out,         // [1024][256]
    int i_val)
{
    __shared__ float a_s[4][512];          // A[b, :, j, :] flattened (i*8+h)
    __shared__ float h_s[4][DD];
    __shared__ float partials[4][4][2];
    const int t = threadIdx.x;
    const int b = blockIdx.x, jg = blockIdx.y;
    const int j0 = jg * 4;
    const float* Ab = A + (long)b * (64 * 64 * 8);
    for (int e = t; e < 4 * 512; e += 256) {
        int jj = e >> 9, ih = e & 511;
        a_s[jj][ih] = Ab[(ih >> 3) * 512 + (j0 + jj) * 8 + (ih & 7)];
    }
    __syncthreads();
    float acc[4] = {0.f, 0.f, 0.f, 0.f};
    const float* Pb = P + (long)b * 64 * 2048;   // contiguous [i][h][d] = [ih][d]
#pragma unroll 8
    for (int ih = 0; ih < 512; ++ih) {
        float pv = Pb[ih * 256 + t];
        acc[0] = fmaf(a_s[0][ih], pv, acc[0]);
        acc[1] = fmaf(a_s[1][ih], pv, acc[1]);
        acc[2] = fmaf(a_s[2][ih], pv, acc[2]);
        acc[3] = fmaf(a_s[3][ih], pv, acc[3]);
    }
    const int wave = t >> 6, lane = t & 63;
    float tv[4];
#pragma unroll
    for (int jj = 0; jj < 4; ++jj) {
        int row = b * 64 + j0 + jj;
        float lin = acc[jj];
        float shr = lin - tanhf(lin);          // shrink()
        tv[jj] = projx[row * DD + t] + shr;
    }
    for (int jj = 0; jj < 4; ++jj) {
        float s = tv[jj], ss = tv[jj] * tv[jj];
#pragma unroll
        for (int m = 32; m >= 1; m >>= 1) { s += __shfl_xor(s, m); ss += __shfl_xor(ss, m); }
        if (lane == 0) { partials[wave][jj][0] = s; partials[wave][jj][1] = ss; }
    }
    __syncthreads();
#pragma unroll
    for (int jj = 0; jj < 4; ++jj) {
        int row = b * 64 + j0 + jj;
        float s  = partials[0][jj][0] + partials[1][jj][0] + partials[2][jj][0] + partials[3][jj][0];
        float ss = partials[0][jj][1] + partials[1][jj][1] + partials[2][jj][1] + partials[3][jj][1];
        float mean = s * (1.f / 256.f);
        float var  = ss * (1.f / 256.f) - mean * mean;
        float rstd = rsqrtf(var + 1e-5f);
        float nv = (tv[jj] - mean) * rstd;
        float hv = fmaf(shiftb[row * DD + t], nv, scaleb[row * DD + t]);
        h_s[jj][t] = fmaxf(hv, 0.f);
    }
    __syncthreads();
    float acc2[4] = {0.f, 0.f, 0.f, 0.f};
#pragma unroll 4
    for (int d = 0; d < DD; ++d) {
        float w = Wout[d * 256 + t];
        acc2[0] = fmaf(h_s[0][d], w, acc2[0]);
        acc2[1] = fmaf(h_s[1][d], w, acc2[1]);
        acc2[2] = fmaf(h_s[2][d], w, acc2[2]);
        acc2[3] = fmaf(h_s[3][d], w, acc2[3]);
    }
    const float bo = bout[t];
    const bool maskz = (i_val > lengths[b]);
#pragma unroll
    for (int jj = 0; jj < 4; ++jj) {
        int row = b * 64 + j0 + jj;
        float y = tanhf(acc2[jj] + bo);
        h_out[row * DD + t] = maskz ? 0.f : y;
    }
}

// ---------------- final: out[b,d] = sum_i h[b,i,d] * root[b,i] ----------------
__global__ __launch_bounds__(256) void k_final(
    const float* __restrict__ h_buf, const float* __restrict__ root,
    float* __restrict__ out)
{
    const int t = threadIdx.x;
    const int b = blockIdx.x;
    float acc = 0.f;
    for (int i = 0; i < LLEN; ++i)
        acc = fmaf(h_buf[(b * 64 + i) * DD + t], root[b * 64 + i], acc);
    out[b * DD + t] = acc;
}

extern "C" void kernel_launch(void* const* d_in, const int* in_sizes, int n_in,
                              void* d_out, int out_size, void* d_ws, size_t ws_size,
                              hipStream_t stream)
{
    const int*   tokens = (const int*)  d_in[0];
    const float* A      = (const float*)d_in[1];
    const float* root   = (const float*)d_in[2];
    const float* emb    = (const float*)d_in[3];
    const float* Wp     = (const float*)d_in[4];
    const float* bp     = (const float*)d_in[5];
    const float* Wi     = (const float*)d_in[6];
    const float* bi     = (const float*)d_in[7];
    const float* Wo     = (const float*)d_in[8];
    const float* bo     = (const float*)d_in[9];
    float* out = (float*)d_out;

    char* ws = (char*)d_ws;
    int*   lengths = (int*)(ws + 0);
    float* shiftb  = (float*)(ws + 1024);
    float* scaleb  = shiftb + NROWS * DD;
    float* projx   = scaleb + NROWS * DD;
    float* h_buf   = projx  + NROWS * DD;
    float* P       = h_buf  + NROWS * DD;

    hipMemsetAsync(h_buf, 0, (size_t)NROWS * DD * sizeof(float), stream);
    k_setup<<<1, 64, 0, stream>>>(tokens, lengths);
    k_inproj<<<128, 256, 0, stream>>>(tokens, emb, Wi, bi, shiftb, scaleb, projx);
    for (int it = 0; it < 64; ++it) {
        int i_val = 64 - it;   // i runs L..1
        k_proj<<<dim3(8, 32), 256, 0, stream>>>(h_buf, Wp, bp, P);
        k_agg<<<dim3(16, 16), 256, 0, stream>>>(A, P, projx, shiftb, scaleb,
                                                Wo, bo, lengths, h_buf, i_val);
    }
    k_final<<<16, 256, 0, stream>>>(h_buf, root, out);
}

// Round 2
// 3248.928 us; speedup vs baseline: 2.1013x; 2.1013x over previous
//
#include <hip/hip_runtime.h>
#include <hip/hip_bf16.h>

// WeightedGNN forward, MI355X. Round 2: k_proj -> bf16 MFMA (16x16x32), no-LDS K-loop.
// B=16, L=64, D=256, NRELS=8. 64 sequential recurrence steps.

#define DD 256
#define LLEN 64
#define BBAT 16
#define NROWS 1024   // B*L

typedef __attribute__((ext_vector_type(8))) short short8;   // 8 bf16 = 4 VGPRs
typedef __attribute__((ext_vector_type(4))) float f32x4;

__device__ inline unsigned short f2bf(float x) {
    unsigned int u = __float_as_uint(x);
    unsigned int r = (u + 0x7fffu + ((u >> 16) & 1u)) >> 16;
    return (unsigned short)r;
}

// ---------------- setup: lengths[b] = count(tokens[:,b] != 0) ----------------
__global__ void k_setup(const int* __restrict__ tokens, int* __restrict__ lengths) {
    int b = threadIdx.x;
    if (b < BBAT) {
        int c = 0;
        for (int l = 0; l < LLEN; ++l) c += (tokens[l * BBAT + b] != 0) ? 1 : 0;
        lengths[b] = c;
    }
}

// ------- one-time: repack W_proj [256][2048] fp32 -> bf16 B-fragment layout -------
// Wf[((hh*16+tn)*8+tk)*512 + lane*8 + j] = W[tk*32 + (lane>>4)*8 + j][hh*256 + tn*16 + (lane&15)]
__global__ __launch_bounds__(256) void k_cvtW(const float* __restrict__ Wp,
                                              unsigned short* __restrict__ Wf) {
    int t = blockIdx.x * 256 + threadIdx.x;   // 65536 total
    int l = t & 63; int rest = t >> 6;
    int tk = rest & 7; rest >>= 3;
    int tn = rest & 15; int hh = rest >> 4;
    int kbase = tk * 32 + (l >> 4) * 8;
    int n = hh * 256 + tn * 16 + (l & 15);
    union { short8 v; unsigned short u[8]; } pk;
#pragma unroll
    for (int j = 0; j < 8; ++j) pk.u[j] = f2bf(Wp[(kbase + j) * 2048 + n]);
    *(short8*)(Wf + (long)t * 8) = pk.v;
}

// ---------------- in_proj: gather emb + [1024x256]@[256x768] -----------------
__global__ __launch_bounds__(256) void k_inproj(
    const int* __restrict__ tokens, const float* __restrict__ emb,
    const float* __restrict__ W_in, const float* __restrict__ b_in,
    float* __restrict__ shiftb, float* __restrict__ scaleb, float* __restrict__ projx)
{
    __shared__ float xs[8][DD];
    const int t = threadIdx.x;
    const int row0 = blockIdx.x * 8;
    for (int r = 0; r < 8; ++r) {
        int row = row0 + r;
        int b = row >> 6, l = row & 63;
        int tok = tokens[l * BBAT + b];
        xs[r][t] = emb[(long)tok * DD + t];
    }
    __syncthreads();
    float a0[8], a1[8], a2[8];
#pragma unroll
    for (int r = 0; r < 8; ++r) { a0[r] = a1[r] = a2[r] = 0.f; }
    for (int k = 0; k < DD; ++k) {
        float w0 = W_in[k * 768 + t];
        float w1 = W_in[k * 768 + 256 + t];
        float w2 = W_in[k * 768 + 512 + t];
#pragma unroll
        for (int r = 0; r < 8; ++r) {
            float x = xs[r][k];
            a0[r] = fmaf(x, w0, a0[r]);
            a1[r] = fmaf(x, w1, a1[r]);
            a2[r] = fmaf(x, w2, a2[r]);
        }
    }
    float bi0 = b_in[t], bi1 = b_in[256 + t], bi2 = b_in[512 + t];
#pragma unroll
    for (int r = 0; r < 8; ++r) {
        int row = row0 + r;
        shiftb[row * DD + t] = a0[r] + bi0;
        scaleb[row * DD + t] = a1[r] + bi1;
        projx [row * DD + t] = a2[r] + bi2;
    }
}

// ------- per-iter MFMA: P = LN_perchunk(h @ W_proj + b_proj) ------------------
// grid (8 h-chunks, 64 rowgroups of 16). Block = 4 waves; wave wv covers cols
// [wv*64, wv*64+64) of the 256-col chunk via 4 ntiles of 16. K=256 = 8 ktiles of 32.
// A-fragments read straight from h_bf (row-major bf16); B-fragments from Wf.
__global__ __launch_bounds__(256) void k_proj(
    const unsigned short* __restrict__ h_bf,   // [1024][256] bf16
    const unsigned short* __restrict__ Wf,     // fragment-packed W_proj bf16
    const float* __restrict__ bp,              // [2048]
    float* __restrict__ P)                     // [1024][2048] fp32
{
    __shared__ float Cs[16][260];
    __shared__ float part[4][16][2];
    const int t = threadIdx.x;
    const int wv = t >> 6, lane = t & 63;
    const int hh = blockIdx.x;
    const int row0 = blockIdx.y * 16;

    f32x4 acc[4];
#pragma unroll
    for (int tn = 0; tn < 4; ++tn) acc[tn] = (f32x4){0.f, 0.f, 0.f, 0.f};

    const unsigned short* aRow = h_bf + (row0 + (lane & 15)) * DD + (lane >> 4) * 8;
    const unsigned short* wBase = Wf + ((long)(hh * 16 + wv * 4) * 8) * 512 + lane * 8;
#pragma unroll
    for (int tk = 0; tk < 8; ++tk) {
        short8 a = *(const short8*)(aRow + tk * 32);
#pragma unroll
        for (int tn = 0; tn < 4; ++tn) {
            short8 b = *(const short8*)(wBase + (long)(tn * 8 + tk) * 512);
            acc[tn] = __builtin_amdgcn_mfma_f32_16x16x32_bf16(a, b, acc[tn], 0, 0, 0);
        }
    }
    // scatter C fragments to LDS: D[m][n], m=(lane>>4)*4+reg, n=lane&15 (+tile offs)
#pragma unroll
    for (int tn = 0; tn < 4; ++tn) {
        int n = wv * 64 + tn * 16 + (lane & 15);
        int m0 = (lane >> 4) * 4;
#pragma unroll
        for (int r = 0; r < 4; ++r) Cs[m0 + r][n] = acc[tn][r];
    }
    __syncthreads();
    // LN over the 256 cols (threads) per row, bias added first
    const float bias = bp[hh * 256 + t];
    float vals[16];
#pragma unroll
    for (int r = 0; r < 16; ++r) vals[r] = Cs[r][t] + bias;
    for (int r = 0; r < 16; ++r) {
        float s = vals[r], ss = vals[r] * vals[r];
#pragma unroll
        for (int m = 32; m >= 1; m >>= 1) { s += __shfl_xor(s, m); ss += __shfl_xor(ss, m); }
        if (lane == 0) { part[wv][r][0] = s; part[wv][r][1] = ss; }
    }
    __syncthreads();
#pragma unroll
    for (int r = 0; r < 16; ++r) {
        float s  = part[0][r][0] + part[1][r][0] + part[2][r][0] + part[3][r][0];
        float ss = part[0][r][1] + part[1][r][1] + part[2][r][1] + part[3][r][1];
        float mean = s * (1.f / 256.f);
        float var  = ss * (1.f / 256.f) - mean * mean;
        float rstd = rsqrtf(var + 1e-5f);
        P[(long)(row0 + r) * 2048 + hh * 256 + t] = (vals[r] - mean) * rstd;
    }
}

// ------- per-iter: lin_sum -> shrink -> LN -> gate -> W_out -> tanh -> mask ---
__global__ __launch_bounds__(256) void k_agg(
    const float* __restrict__ A,       // [16][64][64][8]  (b, i, j, h)
    const float* __restrict__ P,       // [1024][2048]
    const float* __restrict__ projx,
    const float* __restrict__ shiftb,
    const float* __restrict__ scaleb,
    const float* __restrict__ Wout,    // [256][256]
    const float* __restrict__ bout,    // [256]
    const int* __restrict__ lengths,
    float* __restrict__ h_out,         // [1024][256] fp32 (for k_final)
    unsigned short* __restrict__ h_bf, // [1024][256] bf16 (for next k_proj)
    int i_val)
{
    __shared__ float a_s[4][512];
    __shared__ float h_s[4][DD];
    __shared__ float partials[4][4][2];
    const int t = threadIdx.x;
    const int b = blockIdx.x, jg = blockIdx.y;
    const int j0 = jg * 4;
    const float* Ab = A + (long)b * (64 * 64 * 8);
    for (int e = t; e < 4 * 512; e += 256) {
        int jj = e >> 9, ih = e & 511;
        a_s[jj][ih] = Ab[(ih >> 3) * 512 + (j0 + jj) * 8 + (ih & 7)];
    }
    __syncthreads();
    float acc[4] = {0.f, 0.f, 0.f, 0.f};
    const float* Pb = P + (long)b * 64 * 2048;
#pragma unroll 8
    for (int ih = 0; ih < 512; ++ih) {
        float pv = Pb[ih * 256 + t];
        acc[0] = fmaf(a_s[0][ih], pv, acc[0]);
        acc[1] = fmaf(a_s[1][ih], pv, acc[1]);
        acc[2] = fmaf(a_s[2][ih], pv, acc[2]);
        acc[3] = fmaf(a_s[3][ih], pv, acc[3]);
    }
    const int wave = t >> 6, lane = t & 63;
    float tv[4];
#pragma unroll
    for (int jj = 0; jj < 4; ++jj) {
        int row = b * 64 + j0 + jj;
        float lin = acc[jj];
        float shr = lin - tanhf(lin);
        tv[jj] = projx[row * DD + t] + shr;
    }
    for (int jj = 0; jj < 4; ++jj) {
        float s = tv[jj], ss = tv[jj] * tv[jj];
#pragma unroll
        for (int m = 32; m >= 1; m >>= 1) { s += __shfl_xor(s, m); ss += __shfl_xor(ss, m); }
        if (lane == 0) { partials[wave][jj][0] = s; partials[wave][jj][1] = ss; }
    }
    __syncthreads();
#pragma unroll
    for (int jj = 0; jj < 4; ++jj) {
        int row = b * 64 + j0 + jj;
        float s  = partials[0][jj][0] + partials[1][jj][0] + partials[2][jj][0] + partials[3][jj][0];
        float ss = partials[0][jj][1] + partials[1][jj][1] + partials[2][jj][1] + partials[3][jj][1];
        float mean = s * (1.f / 256.f);
        float var  = ss * (1.f / 256.f) - mean * mean;
        float rstd = rsqrtf(var + 1e-5f);
        float nv = (tv[jj] - mean) * rstd;
        float hv = fmaf(shiftb[row * DD + t], nv, scaleb[row * DD + t]);
        h_s[jj][t] = fmaxf(hv, 0.f);
    }
    __syncthreads();
    float acc2[4] = {0.f, 0.f, 0.f, 0.f};
#pragma unroll 4
    for (int d = 0; d < DD; ++d) {
        float w = Wout[d * 256 + t];
        acc2[0] = fmaf(h_s[0][d], w, acc2[0]);
        acc2[1] = fmaf(h_s[1][d], w, acc2[1]);
        acc2[2] = fmaf(h_s[2][d], w, acc2[2]);
        acc2[3] = fmaf(h_s[3][d], w, acc2[3]);
    }
    const float bo = bout[t];
    const bool maskz = (i_val > lengths[b]);
#pragma unroll
    for (int jj = 0; jj < 4; ++jj) {
        int row = b * 64 + j0 + jj;
        float y = tanhf(acc2[jj] + bo);
        float ym = maskz ? 0.f : y;
        h_out[row * DD + t] = ym;
        h_bf[row * DD + t] = f2bf(ym);
    }
}

// ---------------- final: out[b,d] = sum_i h[b,i,d] * root[b,i] ----------------
__global__ __launch_bounds__(256) void k_final(
    const float* __restrict__ h_buf, const float* __restrict__ root,
    float* __restrict__ out)
{
    const int t = threadIdx.x;
    const int b = blockIdx.x;
    float acc = 0.f;
    for (int i = 0; i < LLEN; ++i)
        acc = fmaf(h_buf[(b * 64 + i) * DD + t], root[b * 64 + i], acc);
    out[b * DD + t] = acc;
}

extern "C" void kernel_launch(void* const* d_in, const int* in_sizes, int n_in,
                              void* d_out, int out_size, void* d_ws, size_t ws_size,
                              hipStream_t stream)
{
    const int*   tokens = (const int*)  d_in[0];
    const float* A      = (const float*)d_in[1];
    const float* root   = (const float*)d_in[2];
    const float* emb    = (const float*)d_in[3];
    const float* Wp     = (const float*)d_in[4];
    const float* bp     = (const float*)d_in[5];
    const float* Wi     = (const float*)d_in[6];
    const float* bi     = (const float*)d_in[7];
    const float* Wo     = (const float*)d_in[8];
    const float* bo     = (const float*)d_in[9];
    float* out = (float*)d_out;

    char* ws = (char*)d_ws;
    int*   lengths = (int*)(ws + 0);
    float* shiftb  = (float*)(ws + 1024);
    float* scaleb  = shiftb + NROWS * DD;
    float* projx   = scaleb + NROWS * DD;
    float* h_buf   = projx  + NROWS * DD;
    float* P       = h_buf  + NROWS * DD;              // [1024][2048] fp32, 8 MB
    unsigned short* h_bf = (unsigned short*)(P + (long)NROWS * 2048);  // 0.5 MB
    unsigned short* Wf   = h_bf + NROWS * DD;          // 1 MB

    hipMemsetAsync(h_buf, 0, (size_t)NROWS * DD * sizeof(float), stream);
    hipMemsetAsync(h_bf, 0, (size_t)NROWS * DD * sizeof(unsigned short), stream);
    k_setup<<<1, 64, 0, stream>>>(tokens, lengths);
    k_cvtW<<<256, 256, 0, stream>>>(Wp, Wf);
    k_inproj<<<128, 256, 0, stream>>>(tokens, emb, Wi, bi, shiftb, scaleb, projx);
    for (int it = 0; it < 64; ++it) {
        int i_val = 64 - it;   // i runs L..1
        k_proj<<<dim3(8, 64), 256, 0, stream>>>(h_bf, Wf, bp, P);
        k_agg<<<dim3(16, 16), 256, 0, stream>>>(A, P, projx, shiftb, scaleb,
                                                Wo, bo, lengths, h_buf, h_bf, i_val);
    }
    k_final<<<16, 256, 0, stream>>>(h_buf, root, out);
}

// Round 3
// 2699.407 us; speedup vs baseline: 2.5290x; 1.2036x over previous
//
#include <hip/hip_runtime.h>
#include <hip/hip_bf16.h>

// WeightedGNN forward, MI355X. Round 3: both per-iter GEMMs on MFMA, all operands
// fragment-packed bf16 (A_rels repacked once: kills the 7.7MB/iter HBM re-fetch).
// B=16, L=64, D=256, NRELS=8. 64 sequential recurrence steps.

#define DD 256
#define LLEN 64
#define BBAT 16
#define NROWS 1024   // B*L

typedef __attribute__((ext_vector_type(8))) short short8;   // 8 bf16 = 4 VGPRs
typedef __attribute__((ext_vector_type(4))) float f32x4;

__device__ inline unsigned short f2bf(float x) {
    unsigned int u = __float_as_uint(x);
    unsigned int r = (u + 0x7fffu + ((u >> 16) & 1u)) >> 16;
    return (unsigned short)r;
}

// ---------------- setup: lengths[b] = count(tokens[:,b] != 0) ----------------
__global__ void k_setup(const int* __restrict__ tokens, int* __restrict__ lengths) {
    int b = threadIdx.x;
    if (b < BBAT) {
        int c = 0;
        for (int l = 0; l < LLEN; ++l) c += (tokens[l * BBAT + b] != 0) ? 1 : 0;
        lengths[b] = c;
    }
}

// ------- one-time: W_proj [256][2048] fp32 -> bf16 B-fragment layout ----------
__global__ __launch_bounds__(256) void k_cvtW(const float* __restrict__ Wp,
                                              unsigned short* __restrict__ Wf) {
    int t = blockIdx.x * 256 + threadIdx.x;   // 65536
    int l = t & 63; int rest = t >> 6;
    int tk = rest & 7; rest >>= 3;
    int tn = rest & 15; int hh = rest >> 4;
    int kbase = tk * 32 + (l >> 4) * 8;
    int n = hh * 256 + tn * 16 + (l & 15);
    union { short8 v; unsigned short u[8]; } pk;
#pragma unroll
    for (int j = 0; j < 8; ++j) pk.u[j] = f2bf(Wp[(kbase + j) * 2048 + n]);
    *(short8*)(Wf + (long)t * 8) = pk.v;
}

// ------- one-time: A_rels [16][64][64][8] fp32 -> bf16 A-fragment layout -------
// Af[b][jg(4)][tk(16)][lane(64)][8]: A'[m=j0+(lane&15)][k=tk*32+(lane>>4)*8+jj]
// k=ih=i*8+h, kbase%8==0 -> fixed i, jj=h -> 8 contiguous floats in A. 1 MB total.
__global__ __launch_bounds__(256) void k_cvtA(const float* __restrict__ A,
                                              unsigned short* __restrict__ Af) {
    int t = blockIdx.x * 256 + threadIdx.x;   // 65536
    int lane = t & 63;
    int tk = (t >> 6) & 15;
    int jg = (t >> 10) & 3;
    int b  = t >> 12;
    int j = jg * 16 + (lane & 15);
    int kbase = tk * 32 + (lane >> 4) * 8;
    int i = kbase >> 3;
    const float* src = A + (((long)(b * 64 + i) * 64 + j) * 8);
    float4 v0 = *(const float4*)(src);
    float4 v1 = *(const float4*)(src + 4);
    union { short8 v; unsigned short u[8]; } pk;
    pk.u[0] = f2bf(v0.x); pk.u[1] = f2bf(v0.y); pk.u[2] = f2bf(v0.z); pk.u[3] = f2bf(v0.w);
    pk.u[4] = f2bf(v1.x); pk.u[5] = f2bf(v1.y); pk.u[6] = f2bf(v1.z); pk.u[7] = f2bf(v1.w);
    *(short8*)(Af + (long)t * 8) = pk.v;
}

// ------- one-time: W_out [256][256] fp32 -> bf16 B-fragment layout ------------
__global__ __launch_bounds__(256) void k_cvtWo(const float* __restrict__ Wo,
                                               unsigned short* __restrict__ Wof) {
    int t = blockIdx.x * 256 + threadIdx.x;   // 8192
    int lane = t & 63;
    int tk = (t >> 6) & 7;
    int nt = t >> 9;
    int kbase = tk * 32 + (lane >> 4) * 8;
    int n = nt * 16 + (lane & 15);
    union { short8 v; unsigned short u[8]; } pk;
#pragma unroll
    for (int j = 0; j < 8; ++j) pk.u[j] = f2bf(Wo[(kbase + j) * 256 + n]);
    *(short8*)(Wof + (long)t * 8) = pk.v;
}

// ---------------- in_proj: gather emb + [1024x256]@[256x768] -----------------
__global__ __launch_bounds__(256) void k_inproj(
    const int* __restrict__ tokens, const float* __restrict__ emb,
    const float* __restrict__ W_in, const float* __restrict__ b_in,
    float* __restrict__ shiftb, float* __restrict__ scaleb, float* __restrict__ projx)
{
    __shared__ float xs[8][DD];
    const int t = threadIdx.x;
    const int row0 = blockIdx.x * 8;
    for (int r = 0; r < 8; ++r) {
        int row = row0 + r;
        int b = row >> 6, l = row & 63;
        int tok = tokens[l * BBAT + b];
        xs[r][t] = emb[(long)tok * DD + t];
    }
    __syncthreads();
    float a0[8], a1[8], a2[8];
#pragma unroll
    for (int r = 0; r < 8; ++r) { a0[r] = a1[r] = a2[r] = 0.f; }
    for (int k = 0; k < DD; ++k) {
        float w0 = W_in[k * 768 + t];
        float w1 = W_in[k * 768 + 256 + t];
        float w2 = W_in[k * 768 + 512 + t];
#pragma unroll
        for (int r = 0; r < 8; ++r) {
            float x = xs[r][k];
            a0[r] = fmaf(x, w0, a0[r]);
            a1[r] = fmaf(x, w1, a1[r]);
            a2[r] = fmaf(x, w2, a2[r]);
        }
    }
    float bi0 = b_in[t], bi1 = b_in[256 + t], bi2 = b_in[512 + t];
#pragma unroll
    for (int r = 0; r < 8; ++r) {
        int row = row0 + r;
        shiftb[row * DD + t] = a0[r] + bi0;
        scaleb[row * DD + t] = a1[r] + bi1;
        projx [row * DD + t] = a2[r] + bi2;
    }
}

// ------- per-iter MFMA: Pf = LN_perchunk(h @ W_proj + b_proj), frag-packed bf16 --
// Same structure as round 2 (validated); only the final store changed:
// Pf[b][tk1=i>>2][nt1=d>>4][lane'=(i&3)*16+(d&15)][j=hh] bf16.
__global__ __launch_bounds__(256) void k_proj(
    const unsigned short* __restrict__ h_bf,   // [1024][256] bf16 row-major
    const unsigned short* __restrict__ Wf,     // fragment-packed W_proj
    const float* __restrict__ bp,              // [2048]
    unsigned short* __restrict__ Pf)           // [16][16][16][64][8] bf16
{
    __shared__ float Cs[16][260];
    __shared__ float part[4][16][2];
    const int t = threadIdx.x;
    const int wv = t >> 6, lane = t & 63;
    const int hh = blockIdx.x;
    const int row0 = blockIdx.y * 16;

    f32x4 acc[4];
#pragma unroll
    for (int tn = 0; tn < 4; ++tn) acc[tn] = (f32x4){0.f, 0.f, 0.f, 0.f};

    const unsigned short* aRow = h_bf + (row0 + (lane & 15)) * DD + (lane >> 4) * 8;
    const unsigned short* wBase = Wf + ((long)(hh * 16 + wv * 4) * 8) * 512 + lane * 8;
#pragma unroll
    for (int tk = 0; tk < 8; ++tk) {
        short8 a = *(const short8*)(aRow + tk * 32);
#pragma unroll
        for (int tn = 0; tn < 4; ++tn) {
            short8 b = *(const short8*)(wBase + (long)(tn * 8 + tk) * 512);
            acc[tn] = __builtin_amdgcn_mfma_f32_16x16x32_bf16(a, b, acc[tn], 0, 0, 0);
        }
    }
#pragma unroll
    for (int tn = 0; tn < 4; ++tn) {
        int n = wv * 64 + tn * 16 + (lane & 15);
        int m0 = (lane >> 4) * 4;
#pragma unroll
        for (int r = 0; r < 4; ++r) Cs[m0 + r][n] = acc[tn][r];
    }
    __syncthreads();
    const float bias = bp[hh * 256 + t];
    float vals[16];
#pragma unroll
    for (int r = 0; r < 16; ++r) vals[r] = Cs[r][t] + bias;
    for (int r = 0; r < 16; ++r) {
        float s = vals[r], ss = vals[r] * vals[r];
#pragma unroll
        for (int m = 32; m >= 1; m >>= 1) { s += __shfl_xor(s, m); ss += __shfl_xor(ss, m); }
        if (lane == 0) { part[wv][r][0] = s; part[wv][r][1] = ss; }
    }
    __syncthreads();
#pragma unroll
    for (int r = 0; r < 16; ++r) {
        float s  = part[0][r][0] + part[1][r][0] + part[2][r][0] + part[3][r][0];
        float ss = part[0][r][1] + part[1][r][1] + part[2][r][1] + part[3][r][1];
        float mean = s * (1.f / 256.f);
        float var  = ss * (1.f / 256.f) - mean * mean;
        float rstd = rsqrtf(var + 1e-5f);
        int row = row0 + r;
        int b = row >> 6, i = row & 63;
        long off = (long)b * 131072 + (i >> 2) * 8192 + (t >> 4) * 512
                 + (i & 3) * 128 + (t & 15) * 8 + hh;
        Pf[off] = f2bf((vals[r] - mean) * rstd);
    }
}

// ------- per-iter: MFMA agg + shrink/LN/gate + MFMA W_out + tanh + mask -------
// grid (16 b, 4 jg of 16 j). GEMM1: [16x512]@[512x256] from Af/Pf fragments.
__global__ __launch_bounds__(256) void k_agg(
    const unsigned short* __restrict__ Af,     // [16][4][16][64][8]
    const unsigned short* __restrict__ Pf,     // [16][16][16][64][8]
    const float* __restrict__ projx,
    const float* __restrict__ shiftb,
    const float* __restrict__ scaleb,
    const unsigned short* __restrict__ Wof,    // [16][8][64][8]
    const float* __restrict__ bout,
    const int* __restrict__ lengths,
    float* __restrict__ h_out,                 // [1024][256] fp32 (last iter only)
    unsigned short* __restrict__ h_bf,         // [1024][256] bf16
    int i_val, int write_f32)
{
    __shared__ float Cs[16][260];
    __shared__ unsigned short hsb[16][264];
    __shared__ float part[4][16][2];
    const int t = threadIdx.x;
    const int wv = t >> 6, lane = t & 63;
    const int b = blockIdx.x, jg = blockIdx.y;
    const int j0 = jg * 16;

    // ---- GEMM1: lin = A' @ P ----
    f32x4 acc[4];
#pragma unroll
    for (int nt = 0; nt < 4; ++nt) acc[nt] = (f32x4){0.f, 0.f, 0.f, 0.f};
    const unsigned short* ab = Af + ((long)(b * 4 + jg) * 16) * 512 + lane * 8;
    const unsigned short* pb = Pf + (long)b * 131072 + (wv * 4) * 512 + lane * 8;
#pragma unroll
    for (int tk = 0; tk < 16; ++tk) {
        short8 a = *(const short8*)(ab + tk * 512);
#pragma unroll
        for (int nt = 0; nt < 4; ++nt) {
            short8 bb = *(const short8*)(pb + (long)(tk * 16 + nt) * 512);
            acc[nt] = __builtin_amdgcn_mfma_f32_16x16x32_bf16(a, bb, acc[nt], 0, 0, 0);
        }
    }
#pragma unroll
    for (int nt = 0; nt < 4; ++nt) {
        int n = wv * 64 + nt * 16 + (lane & 15);
        int m0 = (lane >> 4) * 4;
#pragma unroll
        for (int r = 0; r < 4; ++r) Cs[m0 + r][n] = acc[nt][r];
    }
    __syncthreads();

    // ---- epilogue 1: shrink, +projx, LN over d, gate, relu -> hsb (bf16) ----
    float tv[16];
#pragma unroll
    for (int r = 0; r < 16; ++r) {
        int row = b * 64 + j0 + r;
        float lin = Cs[r][t];
        float shr = lin - tanhf(lin);
        tv[r] = projx[row * DD + t] + shr;
    }
    for (int r = 0; r < 16; ++r) {
        float s = tv[r], ss = tv[r] * tv[r];
#pragma unroll
        for (int m = 32; m >= 1; m >>= 1) { s += __shfl_xor(s, m); ss += __shfl_xor(ss, m); }
        if (lane == 0) { part[wv][r][0] = s; part[wv][r][1] = ss; }
    }
    __syncthreads();
#pragma unroll
    for (int r = 0; r < 16; ++r) {
        int row = b * 64 + j0 + r;
        float s  = part[0][r][0] + part[1][r][0] + part[2][r][0] + part[3][r][0];
        float ss = part[0][r][1] + part[1][r][1] + part[2][r][1] + part[3][r][1];
        float mean = s * (1.f / 256.f);
        float var  = ss * (1.f / 256.f) - mean * mean;
        float rstd = rsqrtf(var + 1e-5f);
        float nv = (tv[r] - mean) * rstd;
        float hv = fmaf(shiftb[row * DD + t], nv, scaleb[row * DD + t]);
        hsb[r][t] = f2bf(fmaxf(hv, 0.f));
    }
    __syncthreads();

    // ---- GEMM2: y = h @ W_out (A from LDS, B frag-packed global) ----
    f32x4 acc2[4];
#pragma unroll
    for (int nt = 0; nt < 4; ++nt) acc2[nt] = (f32x4){0.f, 0.f, 0.f, 0.f};
#pragma unroll
    for (int tk = 0; tk < 8; ++tk) {
        short8 a = *(const short8*)(&hsb[lane & 15][tk * 32 + (lane >> 4) * 8]);
#pragma unroll
        for (int nt = 0; nt < 4; ++nt) {
            short8 w = *(const short8*)(Wof + (long)((wv * 4 + nt) * 8 + tk) * 512 + lane * 8);
            acc2[nt] = __builtin_amdgcn_mfma_f32_16x16x32_bf16(a, w, acc2[nt], 0, 0, 0);
        }
    }
    // Cs phase-1 reads all happened before the previous barrier -> safe to overwrite
#pragma unroll
    for (int nt = 0; nt < 4; ++nt) {
        int n = wv * 64 + nt * 16 + (lane & 15);
        int m0 = (lane >> 4) * 4;
#pragma unroll
        for (int r = 0; r < 4; ++r) Cs[m0 + r][n] = acc2[nt][r];
    }
    __syncthreads();
    const float bo_t = bout[t];
    const bool maskz = (i_val > lengths[b]);
#pragma unroll
    for (int r = 0; r < 16; ++r) {
        int row = b * 64 + j0 + r;
        float y = tanhf(Cs[r][t] + bo_t);
        float ym = maskz ? 0.f : y;
        h_bf[row * DD + t] = f2bf(ym);
        if (write_f32) h_out[row * DD + t] = ym;
    }
}

// ---------------- final: out[b,d] = sum_i h[b,i,d] * root[b,i] ----------------
__global__ __launch_bounds__(256) void k_final(
    const float* __restrict__ h_buf, const float* __restrict__ root,
    float* __restrict__ out)
{
    const int t = threadIdx.x;
    const int b = blockIdx.x;
    float acc = 0.f;
    for (int i = 0; i < LLEN; ++i)
        acc = fmaf(h_buf[(b * 64 + i) * DD + t], root[b * 64 + i], acc);
    out[b * DD + t] = acc;
}

extern "C" void kernel_launch(void* const* d_in, const int* in_sizes, int n_in,
                              void* d_out, int out_size, void* d_ws, size_t ws_size,
                              hipStream_t stream)
{
    const int*   tokens = (const int*)  d_in[0];
    const float* A      = (const float*)d_in[1];
    const float* root   = (const float*)d_in[2];
    const float* emb    = (const float*)d_in[3];
    const float* Wp     = (const float*)d_in[4];
    const float* bp     = (const float*)d_in[5];
    const float* Wi     = (const float*)d_in[6];
    const float* bi     = (const float*)d_in[7];
    const float* Wo     = (const float*)d_in[8];
    const float* bo     = (const float*)d_in[9];
    float* out = (float*)d_out;

    char* ws = (char*)d_ws;
    int*   lengths = (int*)(ws + 0);
    float* shiftb  = (float*)(ws + 1024);
    float* scaleb  = shiftb + NROWS * DD;
    float* projx   = scaleb + NROWS * DD;
    float* h_out   = projx  + NROWS * DD;                       // 1 MB fp32
    unsigned short* h_bf = (unsigned short*)(h_out + NROWS * DD);  // 512 KB
    unsigned short* Wf   = h_bf + NROWS * DD;                   // 1 MB
    unsigned short* Pf   = Wf + 524288;                         // 4 MB
    unsigned short* Af   = Pf + 2097152;                        // 1 MB
    unsigned short* Wof  = Af + 524288;                         // 128 KB

    hipMemsetAsync(h_bf, 0, (size_t)NROWS * DD * sizeof(unsigned short), stream);
    k_setup<<<1, 64, 0, stream>>>(tokens, lengths);
    k_cvtW<<<256, 256, 0, stream>>>(Wp, Wf);
    k_cvtA<<<256, 256, 0, stream>>>(A, Af);
    k_cvtWo<<<32, 256, 0, stream>>>(Wo, Wof);
    k_inproj<<<128, 256, 0, stream>>>(tokens, emb, Wi, bi, shiftb, scaleb, projx);
    for (int it = 0; it < 64; ++it) {
        int i_val = 64 - it;   // i runs L..1
        k_proj<<<dim3(8, 64), 256, 0, stream>>>(h_bf, Wf, bp, Pf);
        k_agg<<<dim3(16, 4), 256, 0, stream>>>(Af, Pf, projx, shiftb, scaleb,
                                               Wof, bo, lengths, h_out, h_bf,
                                               i_val, (it == 63) ? 1 : 0);
    }
    k_final<<<16, 256, 0, stream>>>(h_out, root, out);
}

// Round 4
// 2145.289 us; speedup vs baseline: 3.1823x; 1.2583x over previous
//
#include <hip/hip_runtime.h>
#include <hip/hip_bf16.h>

// WeightedGNN forward, MI355X. Round 4: GEMM1 K-ordering flipped to k=h*64+i so
// k_proj writes Pf as coalesced short8 stores (round 3 wrote 16 scattered 2-B
// stores/thread -> ~8x L2 write amplification). k_agg: 1-deep K-loop prefetch.
// B=16, L=64, D=256, NRELS=8. 64 sequential recurrence steps.

#define DD 256
#define LLEN 64
#define BBAT 16
#define NROWS 1024   // B*L

typedef __attribute__((ext_vector_type(8))) short short8;   // 8 bf16 = 4 VGPRs
typedef __attribute__((ext_vector_type(4))) float f32x4;

__device__ inline unsigned short f2bf(float x) {
    unsigned int u = __float_as_uint(x);
    unsigned int r = (u + 0x7fffu + ((u >> 16) & 1u)) >> 16;
    return (unsigned short)r;
}

// ---------------- setup: lengths[b] = count(tokens[:,b] != 0) ----------------
__global__ void k_setup(const int* __restrict__ tokens, int* __restrict__ lengths) {
    int b = threadIdx.x;
    if (b < BBAT) {
        int c = 0;
        for (int l = 0; l < LLEN; ++l) c += (tokens[l * BBAT + b] != 0) ? 1 : 0;
        lengths[b] = c;
    }
}

// ------- one-time: W_proj [256][2048] fp32 -> bf16 B-fragment layout ----------
__global__ __launch_bounds__(256) void k_cvtW(const float* __restrict__ Wp,
                                              unsigned short* __restrict__ Wf) {
    int t = blockIdx.x * 256 + threadIdx.x;   // 65536
    int l = t & 63; int rest = t >> 6;
    int tk = rest & 7; rest >>= 3;
    int tn = rest & 15; int hh = rest >> 4;
    int kbase = tk * 32 + (l >> 4) * 8;
    int n = hh * 256 + tn * 16 + (l & 15);
    union { short8 v; unsigned short u[8]; } pk;
#pragma unroll
    for (int j = 0; j < 8; ++j) pk.u[j] = f2bf(Wp[(kbase + j) * 2048 + n]);
    *(short8*)(Wf + (long)t * 8) = pk.v;
}

// ------- one-time: A_rels -> bf16 A-fragment layout, K-order k = h*64 + i -----
// Af[b][jg(4)][tk(16)][lane(64)][8]: A'[m=jg*16+(lane&15)][k=tk*32+(lane>>4)*8+jj]
// k = h*64+i  ->  h = k>>6, i = k&63; 8-blocks never cross an h boundary.
__global__ __launch_bounds__(256) void k_cvtA(const float* __restrict__ A,
                                              unsigned short* __restrict__ Af) {
    int t = blockIdx.x * 256 + threadIdx.x;   // 65536
    int lane = t & 63;
    int tk = (t >> 6) & 15;
    int jg = (t >> 10) & 3;
    int b  = t >> 12;
    int j = jg * 16 + (lane & 15);
    int kbase = tk * 32 + (lane >> 4) * 8;
    int h  = kbase >> 6;
    int i0 = kbase & 63;
    union { short8 v; unsigned short u[8]; } pk;
#pragma unroll
    for (int jj = 0; jj < 8; ++jj)
        pk.u[jj] = f2bf(A[((long)(b * 64 + i0 + jj) * 64 + j) * 8 + h]);
    *(short8*)(Af + (long)t * 8) = pk.v;
}

// ------- one-time: W_out [256][256] fp32 -> bf16 B-fragment layout ------------
__global__ __launch_bounds__(256) void k_cvtWo(const float* __restrict__ Wo,
                                               unsigned short* __restrict__ Wof) {
    int t = blockIdx.x * 256 + threadIdx.x;   // 8192
    int lane = t & 63;
    int tk = (t >> 6) & 7;
    int nt = t >> 9;
    int kbase = tk * 32 + (lane >> 4) * 8;
    int n = nt * 16 + (lane & 15);
    union { short8 v; unsigned short u[8]; } pk;
#pragma unroll
    for (int j = 0; j < 8; ++j) pk.u[j] = f2bf(Wo[(kbase + j) * 256 + n]);
    *(short8*)(Wof + (long)t * 8) = pk.v;
}

// ---------------- in_proj: gather emb + [1024x256]@[256x768] -----------------
__global__ __launch_bounds__(256) void k_inproj(
    const int* __restrict__ tokens, const float* __restrict__ emb,
    const float* __restrict__ W_in, const float* __restrict__ b_in,
    float* __restrict__ shiftb, float* __restrict__ scaleb, float* __restrict__ projx)
{
    __shared__ float xs[8][DD];
    const int t = threadIdx.x;
    const int row0 = blockIdx.x * 8;
    for (int r = 0; r < 8; ++r) {
        int row = row0 + r;
        int b = row >> 6, l = row & 63;
        int tok = tokens[l * BBAT + b];
        xs[r][t] = emb[(long)tok * DD + t];
    }
    __syncthreads();
    float a0[8], a1[8], a2[8];
#pragma unroll
    for (int r = 0; r < 8; ++r) { a0[r] = a1[r] = a2[r] = 0.f; }
    for (int k = 0; k < DD; ++k) {
        float w0 = W_in[k * 768 + t];
        float w1 = W_in[k * 768 + 256 + t];
        float w2 = W_in[k * 768 + 512 + t];
#pragma unroll
        for (int r = 0; r < 8; ++r) {
            float x = xs[r][k];
            a0[r] = fmaf(x, w0, a0[r]);
            a1[r] = fmaf(x, w1, a1[r]);
            a2[r] = fmaf(x, w2, a2[r]);
        }
    }
    float bi0 = b_in[t], bi1 = b_in[256 + t], bi2 = b_in[512 + t];
#pragma unroll
    for (int r = 0; r < 8; ++r) {
        int row = row0 + r;
        shiftb[row * DD + t] = a0[r] + bi0;
        scaleb[row * DD + t] = a1[r] + bi1;
        projx [row * DD + t] = a2[r] + bi2;
    }
}

// ------- per-iter MFMA: Pf = LN_perchunk(h @ W_proj + b_proj) ------------------
// Store: thread (hh, d=t) owns rows i = (row0&63)+r; with k = hh*64+i the 8
// consecutive jj of a B-fragment are 8 consecutive i -> two short8 stores.
__global__ __launch_bounds__(256) void k_proj(
    const unsigned short* __restrict__ h_bf,   // [1024][256] bf16 row-major
    const unsigned short* __restrict__ Wf,     // fragment-packed W_proj
    const float* __restrict__ bp,              // [2048]
    unsigned short* __restrict__ Pf)           // [16][tk1 16][nt1 16][64][8] bf16
{
    __shared__ float Cs[16][260];
    __shared__ float part[4][16][2];
    const int t = threadIdx.x;
    const int wv = t >> 6, lane = t & 63;
    const int hh = blockIdx.x;
    const int row0 = blockIdx.y * 16;

    f32x4 acc[4];
#pragma unroll
    for (int tn = 0; tn < 4; ++tn) acc[tn] = (f32x4){0.f, 0.f, 0.f, 0.f};

    const unsigned short* aRow = h_bf + (row0 + (lane & 15)) * DD + (lane >> 4) * 8;
    const unsigned short* wBase = Wf + ((long)(hh * 16 + wv * 4) * 8) * 512 + lane * 8;
#pragma unroll
    for (int tk = 0; tk < 8; ++tk) {
        short8 a = *(const short8*)(aRow + tk * 32);
#pragma unroll
        for (int tn = 0; tn < 4; ++tn) {
            short8 b = *(const short8*)(wBase + (long)(tn * 8 + tk) * 512);
            acc[tn] = __builtin_amdgcn_mfma_f32_16x16x32_bf16(a, b, acc[tn], 0, 0, 0);
        }
    }
#pragma unroll
    for (int tn = 0; tn < 4; ++tn) {
        int n = wv * 64 + tn * 16 + (lane & 15);
        int m0 = (lane >> 4) * 4;
#pragma unroll
        for (int r = 0; r < 4; ++r) Cs[m0 + r][n] = acc[tn][r];
    }
    __syncthreads();
    const float bias = bp[hh * 256 + t];
    float vals[16];
#pragma unroll
    for (int r = 0; r < 16; ++r) vals[r] = Cs[r][t] + bias;
    for (int r = 0; r < 16; ++r) {
        float s = vals[r], ss = vals[r] * vals[r];
#pragma unroll
        for (int m = 32; m >= 1; m >>= 1) { s += __shfl_xor(s, m); ss += __shfl_xor(ss, m); }
        if (lane == 0) { part[wv][r][0] = s; part[wv][r][1] = ss; }
    }
    __syncthreads();
    float normed[16];
#pragma unroll
    for (int r = 0; r < 16; ++r) {
        float s  = part[0][r][0] + part[1][r][0] + part[2][r][0] + part[3][r][0];
        float ss = part[0][r][1] + part[1][r][1] + part[2][r][1] + part[3][r][1];
        float mean = s * (1.f / 256.f);
        float var  = ss * (1.f / 256.f) - mean * mean;
        float rstd = rsqrtf(var + 1e-5f);
        normed[r] = (vals[r] - mean) * rstd;
    }
    const int b = row0 >> 6;
    const int ibase = row0 & 63;
#pragma unroll
    for (int g = 0; g < 2; ++g) {
        int k0 = hh * 64 + ibase + g * 8;                 // 8-aligned
        int tk1 = k0 >> 5;
        int lane_s = ((k0 >> 3) & 3) * 16 + (t & 15);
        long off = (long)b * 131072 + tk1 * 8192 + (t >> 4) * 512 + lane_s * 8;
        union { short8 v; unsigned short u[8]; } pk;
#pragma unroll
        for (int jj = 0; jj < 8; ++jj) pk.u[jj] = f2bf(normed[g * 8 + jj]);
        *(short8*)(Pf + off) = pk.v;
    }
}

// ------- per-iter: MFMA agg + shrink/LN/gate + MFMA W_out + tanh + mask -------
__global__ __launch_bounds__(256) void k_agg(
    const unsigned short* __restrict__ Af,     // [16][4][16][64][8]
    const unsigned short* __restrict__ Pf,     // [16][16][16][64][8]
    const float* __restrict__ projx,
    const float* __restrict__ shiftb,
    const float* __restrict__ scaleb,
    const unsigned short* __restrict__ Wof,    // [16][8][64][8]
    const float* __restrict__ bout,
    const int* __restrict__ lengths,
    float* __restrict__ h_out,                 // [1024][256] fp32 (last iter only)
    unsigned short* __restrict__ h_bf,         // [1024][256] bf16
    int i_val, int write_f32)
{
    __shared__ float Cs[16][260];
    __shared__ unsigned short hsb[16][264];
    __shared__ float part[4][16][2];
    const int t = threadIdx.x;
    const int wv = t >> 6, lane = t & 63;
    const int b = blockIdx.x, jg = blockIdx.y;
    const int j0 = jg * 16;

    // ---- GEMM1: lin = A' @ P, K=512 (k = h*64+i), 1-deep prefetch ----
    f32x4 acc[4];
#pragma unroll
    for (int nt = 0; nt < 4; ++nt) acc[nt] = (f32x4){0.f, 0.f, 0.f, 0.f};
    const unsigned short* ab = Af + ((long)(b * 4 + jg) * 16) * 512 + lane * 8;
    const unsigned short* pb = Pf + (long)b * 131072 + (wv * 4) * 512 + lane * 8;
    short8 a_c = *(const short8*)(ab);
    short8 b_c0 = *(const short8*)(pb + 0 * 512);
    short8 b_c1 = *(const short8*)(pb + 1 * 512);
    short8 b_c2 = *(const short8*)(pb + 2 * 512);
    short8 b_c3 = *(const short8*)(pb + 3 * 512);
#pragma unroll
    for (int tk = 0; tk < 16; ++tk) {
        short8 a_n, b_n0, b_n1, b_n2, b_n3;
        if (tk < 15) {
            a_n  = *(const short8*)(ab + (tk + 1) * 512);
            b_n0 = *(const short8*)(pb + ((tk + 1) * 16 + 0) * 512);
            b_n1 = *(const short8*)(pb + ((tk + 1) * 16 + 1) * 512);
            b_n2 = *(const short8*)(pb + ((tk + 1) * 16 + 2) * 512);
            b_n3 = *(const short8*)(pb + ((tk + 1) * 16 + 3) * 512);
        }
        acc[0] = __builtin_amdgcn_mfma_f32_16x16x32_bf16(a_c, b_c0, acc[0], 0, 0, 0);
        acc[1] = __builtin_amdgcn_mfma_f32_16x16x32_bf16(a_c, b_c1, acc[1], 0, 0, 0);
        acc[2] = __builtin_amdgcn_mfma_f32_16x16x32_bf16(a_c, b_c2, acc[2], 0, 0, 0);
        acc[3] = __builtin_amdgcn_mfma_f32_16x16x32_bf16(a_c, b_c3, acc[3], 0, 0, 0);
        if (tk < 15) { a_c = a_n; b_c0 = b_n0; b_c1 = b_n1; b_c2 = b_n2; b_c3 = b_n3; }
    }
#pragma unroll
    for (int nt = 0; nt < 4; ++nt) {
        int n = wv * 64 + nt * 16 + (lane & 15);
        int m0 = (lane >> 4) * 4;
#pragma unroll
        for (int r = 0; r < 4; ++r) Cs[m0 + r][n] = acc[nt][r];
    }
    __syncthreads();

    // ---- epilogue 1: shrink, +projx, LN over d, gate, relu -> hsb (bf16) ----
    float tv[16];
#pragma unroll
    for (int r = 0; r < 16; ++r) {
        int row = b * 64 + j0 + r;
        float lin = Cs[r][t];
        float shr = lin - tanhf(lin);
        tv[r] = projx[row * DD + t] + shr;
    }
    for (int r = 0; r < 16; ++r) {
        float s = tv[r], ss = tv[r] * tv[r];
#pragma unroll
        for (int m = 32; m >= 1; m >>= 1) { s += __shfl_xor(s, m); ss += __shfl_xor(ss, m); }
        if (lane == 0) { part[wv][r][0] = s; part[wv][r][1] = ss; }
    }
    __syncthreads();
#pragma unroll
    for (int r = 0; r < 16; ++r) {
        int row = b * 64 + j0 + r;
        float s  = part[0][r][0] + part[1][r][0] + part[2][r][0] + part[3][r][0];
        float ss = part[0][r][1] + part[1][r][1] + part[2][r][1] + part[3][r][1];
        float mean = s * (1.f / 256.f);
        float var  = ss * (1.f / 256.f) - mean * mean;
        float rstd = rsqrtf(var + 1e-5f);
        float nv = (tv[r] - mean) * rstd;
        float hv = fmaf(shiftb[row * DD + t], nv, scaleb[row * DD + t]);
        hsb[r][t] = f2bf(fmaxf(hv, 0.f));
    }
    __syncthreads();

    // ---- GEMM2: y = h @ W_out (A from LDS, B frag-packed global) ----
    f32x4 acc2[4];
#pragma unroll
    for (int nt = 0; nt < 4; ++nt) acc2[nt] = (f32x4){0.f, 0.f, 0.f, 0.f};
#pragma unroll
    for (int tk = 0; tk < 8; ++tk) {
        short8 a = *(const short8*)(&hsb[lane & 15][tk * 32 + (lane >> 4) * 8]);
#pragma unroll
        for (int nt = 0; nt < 4; ++nt) {
            short8 w = *(const short8*)(Wof + (long)((wv * 4 + nt) * 8 + tk) * 512 + lane * 8);
            acc2[nt] = __builtin_amdgcn_mfma_f32_16x16x32_bf16(a, w, acc2[nt], 0, 0, 0);
        }
    }
#pragma unroll
    for (int nt = 0; nt < 4; ++nt) {
        int n = wv * 64 + nt * 16 + (lane & 15);
        int m0 = (lane >> 4) * 4;
#pragma unroll
        for (int r = 0; r < 4; ++r) Cs[m0 + r][n] = acc2[nt][r];
    }
    __syncthreads();
    const float bo_t = bout[t];
    const bool maskz = (i_val > lengths[b]);
#pragma unroll
    for (int r = 0; r < 16; ++r) {
        int row = b * 64 + j0 + r;
        float y = tanhf(Cs[r][t] + bo_t);
        float ym = maskz ? 0.f : y;
        h_bf[row * DD + t] = f2bf(ym);
        if (write_f32) h_out[row * DD + t] = ym;
    }
}

// ---------------- final: out[b,d] = sum_i h[b,i,d] * root[b,i] ----------------
__global__ __launch_bounds__(256) void k_final(
    const float* __restrict__ h_buf, const float* __restrict__ root,
    float* __restrict__ out)
{
    const int t = threadIdx.x;
    const int b = blockIdx.x;
    float acc = 0.f;
    for (int i = 0; i < LLEN; ++i)
        acc = fmaf(h_buf[(b * 64 + i) * DD + t], root[b * 64 + i], acc);
    out[b * DD + t] = acc;
}

extern "C" void kernel_launch(void* const* d_in, const int* in_sizes, int n_in,
                              void* d_out, int out_size, void* d_ws, size_t ws_size,
                              hipStream_t stream)
{
    const int*   tokens = (const int*)  d_in[0];
    const float* A      = (const float*)d_in[1];
    const float* root   = (const float*)d_in[2];
    const float* emb    = (const float*)d_in[3];
    const float* Wp     = (const float*)d_in[4];
    const float* bp     = (const float*)d_in[5];
    const float* Wi     = (const float*)d_in[6];
    const float* bi     = (const float*)d_in[7];
    const float* Wo     = (const float*)d_in[8];
    const float* bo     = (const float*)d_in[9];
    float* out = (float*)d_out;

    char* ws = (char*)d_ws;
    int*   lengths = (int*)(ws + 0);
    float* shiftb  = (float*)(ws + 1024);
    float* scaleb  = shiftb + NROWS * DD;
    float* projx   = scaleb + NROWS * DD;
    float* h_out   = projx  + NROWS * DD;                       // 1 MB fp32
    unsigned short* h_bf = (unsigned short*)(h_out + NROWS * DD);  // 512 KB
    unsigned short* Wf   = h_bf + NROWS * DD;                   // 1 MB
    unsigned short* Pf   = Wf + 524288;                         // 4 MB
    unsigned short* Af   = Pf + 2097152;                        // 1 MB
    unsigned short* Wof  = Af + 524288;                         // 128 KB

    hipMemsetAsync(h_bf, 0, (size_t)NROWS * DD * sizeof(unsigned short), stream);
    k_setup<<<1, 64, 0, stream>>>(tokens, lengths);
    k_cvtW<<<256, 256, 0, stream>>>(Wp, Wf);
    k_cvtA<<<256, 256, 0, stream>>>(A, Af);
    k_cvtWo<<<32, 256, 0, stream>>>(Wo, Wof);
    k_inproj<<<128, 256, 0, stream>>>(tokens, emb, Wi, bi, shiftb, scaleb, projx);
    for (int it = 0; it < 64; ++it) {
        int i_val = 64 - it;   // i runs L..1
        k_proj<<<dim3(8, 64), 256, 0, stream>>>(h_bf, Wf, bp, Pf);
        k_agg<<<dim3(16, 4), 256, 0, stream>>>(Af, Pf, projx, shiftb, scaleb,
                                               Wof, bo, lengths, h_out, h_bf,
                                               i_val, (it == 63) ? 1 : 0);
    }
    k_final<<<16, 256, 0, stream>>>(h_out, root, out);
}

// Round 5
// 1586.166 us; speedup vs baseline: 4.3040x; 1.3525x over previous
//
#include <hip/hip_runtime.h>
#include <hip/hip_bf16.h>

// WeightedGNN forward, MI355X. Round 5: k_agg rebuilt for MLP (1024-thr blocks,
// 16 B-fragments preloaded per wave -> ~256 outstanding loads/CU vs ~2) and
// XCD-colocation (proj blocks for batch b pinned to XCD b%8 = agg's XCD).
// B=16, L=64, D=256, NRELS=8. 64 sequential recurrence steps.

#define DD 256
#define LLEN 64
#define BBAT 16
#define NROWS 1024   // B*L

typedef __attribute__((ext_vector_type(8))) short short8;   // 8 bf16 = 4 VGPRs
typedef __attribute__((ext_vector_type(4))) float f32x4;

__device__ inline unsigned short f2bf(float x) {
    unsigned int u = __float_as_uint(x);
    unsigned int r = (u + 0x7fffu + ((u >> 16) & 1u)) >> 16;
    return (unsigned short)r;
}

// ---------------- setup: lengths[b] = count(tokens[:,b] != 0) ----------------
__global__ void k_setup(const int* __restrict__ tokens, int* __restrict__ lengths) {
    int b = threadIdx.x;
    if (b < BBAT) {
        int c = 0;
        for (int l = 0; l < LLEN; ++l) c += (tokens[l * BBAT + b] != 0) ? 1 : 0;
        lengths[b] = c;
    }
}

// ------- one-time: W_proj [256][2048] fp32 -> bf16 B-fragment layout ----------
__global__ __launch_bounds__(256) void k_cvtW(const float* __restrict__ Wp,
                                              unsigned short* __restrict__ Wf) {
    int t = blockIdx.x * 256 + threadIdx.x;   // 65536
    int l = t & 63; int rest = t >> 6;
    int tk = rest & 7; rest >>= 3;
    int tn = rest & 15; int hh = rest >> 4;
    int kbase = tk * 32 + (l >> 4) * 8;
    int n = hh * 256 + tn * 16 + (l & 15);
    union { short8 v; unsigned short u[8]; } pk;
#pragma unroll
    for (int j = 0; j < 8; ++j) pk.u[j] = f2bf(Wp[(kbase + j) * 2048 + n]);
    *(short8*)(Wf + (long)t * 8) = pk.v;
}

// ------- one-time: A_rels -> bf16 A-fragment layout, K-order k = h*64 + i -----
__global__ __launch_bounds__(256) void k_cvtA(const float* __restrict__ A,
                                              unsigned short* __restrict__ Af) {
    int t = blockIdx.x * 256 + threadIdx.x;   // 65536
    int lane = t & 63;
    int tk = (t >> 6) & 15;
    int jg = (t >> 10) & 3;
    int b  = t >> 12;
    int j = jg * 16 + (lane & 15);
    int kbase = tk * 32 + (lane >> 4) * 8;
    int h  = kbase >> 6;
    int i0 = kbase & 63;
    union { short8 v; unsigned short u[8]; } pk;
#pragma unroll
    for (int jj = 0; jj < 8; ++jj)
        pk.u[jj] = f2bf(A[((long)(b * 64 + i0 + jj) * 64 + j) * 8 + h]);
    *(short8*)(Af + (long)t * 8) = pk.v;
}

// ------- one-time: W_out [256][256] fp32 -> bf16 B-fragment layout ------------
__global__ __launch_bounds__(256) void k_cvtWo(const float* __restrict__ Wo,
                                               unsigned short* __restrict__ Wof) {
    int t = blockIdx.x * 256 + threadIdx.x;   // 8192
    int lane = t & 63;
    int tk = (t >> 6) & 7;
    int nt = t >> 9;
    int kbase = tk * 32 + (lane >> 4) * 8;
    int n = nt * 16 + (lane & 15);
    union { short8 v; unsigned short u[8]; } pk;
#pragma unroll
    for (int j = 0; j < 8; ++j) pk.u[j] = f2bf(Wo[(kbase + j) * 256 + n]);
    *(short8*)(Wof + (long)t * 8) = pk.v;
}

// ---------------- in_proj: gather emb + [1024x256]@[256x768] -----------------
__global__ __launch_bounds__(256) void k_inproj(
    const int* __restrict__ tokens, const float* __restrict__ emb,
    const float* __restrict__ W_in, const float* __restrict__ b_in,
    float* __restrict__ shiftb, float* __restrict__ scaleb, float* __restrict__ projx)
{
    __shared__ float xs[8][DD];
    const int t = threadIdx.x;
    const int row0 = blockIdx.x * 8;
    for (int r = 0; r < 8; ++r) {
        int row = row0 + r;
        int b = row >> 6, l = row & 63;
        int tok = tokens[l * BBAT + b];
        xs[r][t] = emb[(long)tok * DD + t];
    }
    __syncthreads();
    float a0[8], a1[8], a2[8];
#pragma unroll
    for (int r = 0; r < 8; ++r) { a0[r] = a1[r] = a2[r] = 0.f; }
    for (int k = 0; k < DD; ++k) {
        float w0 = W_in[k * 768 + t];
        float w1 = W_in[k * 768 + 256 + t];
        float w2 = W_in[k * 768 + 512 + t];
#pragma unroll
        for (int r = 0; r < 8; ++r) {
            float x = xs[r][k];
            a0[r] = fmaf(x, w0, a0[r]);
            a1[r] = fmaf(x, w1, a1[r]);
            a2[r] = fmaf(x, w2, a2[r]);
        }
    }
    float bi0 = b_in[t], bi1 = b_in[256 + t], bi2 = b_in[512 + t];
#pragma unroll
    for (int r = 0; r < 8; ++r) {
        int row = row0 + r;
        shiftb[row * DD + t] = a0[r] + bi0;
        scaleb[row * DD + t] = a1[r] + bi1;
        projx [row * DD + t] = a2[r] + bi2;
    }
}

// ------- per-iter MFMA: Pf = LN_perchunk(h @ W_proj + b_proj) ------------------
// Flat grid 512, decoded so batch b lands on XCD b%8 (blockIdx%8 heuristic).
// A-fragments preloaded (8x16B) for MLP; launch_bounds(256,2) raises VGPR cap.
__global__ __launch_bounds__(256, 2) void k_proj(
    const unsigned short* __restrict__ h_bf,   // [1024][256] bf16 row-major
    const unsigned short* __restrict__ Wf,     // fragment-packed W_proj
    const float* __restrict__ bp,              // [2048]
    unsigned short* __restrict__ Pf)           // [16][tk1 16][nt1 16][64][8] bf16
{
    __shared__ float Cs[16][260];
    __shared__ float part[4][16][2];
    const int t = threadIdx.x;
    const int wv = t >> 6, lane = t & 63;
    // decode: xcd = lin&7 == b%8
    const int lin = blockIdx.x;
    const int xcd = lin & 7, q = lin >> 3;
    const int b = xcd + 8 * (q & 1);
    const int rest = q >> 1;
    const int hh = rest & 7;
    const int ig = rest >> 3;              // 0..3
    const int row0 = b * 64 + ig * 16;

    f32x4 acc[4];
#pragma unroll
    for (int tn = 0; tn < 4; ++tn) acc[tn] = (f32x4){0.f, 0.f, 0.f, 0.f};

    const unsigned short* aRow = h_bf + (row0 + (lane & 15)) * DD + (lane >> 4) * 8;
    const unsigned short* wBase = Wf + ((long)(hh * 16 + wv * 4) * 8) * 512 + lane * 8;
    short8 a8[8];
#pragma unroll
    for (int tk = 0; tk < 8; ++tk) a8[tk] = *(const short8*)(aRow + tk * 32);
#pragma unroll
    for (int tk = 0; tk < 8; ++tk) {
#pragma unroll
        for (int tn = 0; tn < 4; ++tn) {
            short8 bb = *(const short8*)(wBase + (long)(tn * 8 + tk) * 512);
            acc[tn] = __builtin_amdgcn_mfma_f32_16x16x32_bf16(a8[tk], bb, acc[tn], 0, 0, 0);
        }
    }
#pragma unroll
    for (int tn = 0; tn < 4; ++tn) {
        int n = wv * 64 + tn * 16 + (lane & 15);
        int m0 = (lane >> 4) * 4;
#pragma unroll
        for (int r = 0; r < 4; ++r) Cs[m0 + r][n] = acc[tn][r];
    }
    __syncthreads();
    const float bias = bp[hh * 256 + t];
    float vals[16];
#pragma unroll
    for (int r = 0; r < 16; ++r) vals[r] = Cs[r][t] + bias;
    for (int r = 0; r < 16; ++r) {
        float s = vals[r], ss = vals[r] * vals[r];
#pragma unroll
        for (int m = 32; m >= 1; m >>= 1) { s += __shfl_xor(s, m); ss += __shfl_xor(ss, m); }
        if (lane == 0) { part[wv][r][0] = s; part[wv][r][1] = ss; }
    }
    __syncthreads();
    float normed[16];
#pragma unroll
    for (int r = 0; r < 16; ++r) {
        float s  = part[0][r][0] + part[1][r][0] + part[2][r][0] + part[3][r][0];
        float ss = part[0][r][1] + part[1][r][1] + part[2][r][1] + part[3][r][1];
        float mean = s * (1.f / 256.f);
        float var  = ss * (1.f / 256.f) - mean * mean;
        float rstd = rsqrtf(var + 1e-5f);
        normed[r] = (vals[r] - mean) * rstd;
    }
    const int ibase = ig * 16;
#pragma unroll
    for (int g = 0; g < 2; ++g) {
        int k0 = hh * 64 + ibase + g * 8;                 // 8-aligned
        int tk1 = k0 >> 5;
        int lane_s = ((k0 >> 3) & 3) * 16 + (t & 15);
        long off = (long)b * 131072 + tk1 * 8192 + (t >> 4) * 512 + lane_s * 8;
        union { short8 v; unsigned short u[8]; } pk;
#pragma unroll
        for (int jj = 0; jj < 8; ++jj) pk.u[jj] = f2bf(normed[g * 8 + jj]);
        *(short8*)(Pf + off) = pk.v;
    }
}

// ------- per-iter: MFMA agg + shrink/LN/gate + MFMA W_out + tanh + mask -------
// 1024 threads = 16 waves; wave w owns n-tile nt=w. All 16 B-fragments preloaded
// -> 16 outstanding loads/wave, 16 waves/CU. grid (16 b, 4 jg): lin%8 = b%8.
__global__ __launch_bounds__(1024) void k_agg(
    const unsigned short* __restrict__ Af,     // [16][4][16][64][8]
    const unsigned short* __restrict__ Pf,     // [16][16][16][64][8]
    const float* __restrict__ projx,
    const float* __restrict__ shiftb,
    const float* __restrict__ scaleb,
    const unsigned short* __restrict__ Wof,    // [16 nt][8 tk][64][8]
    const float* __restrict__ bout,
    const int* __restrict__ lengths,
    float* __restrict__ h_out,                 // [1024][256] fp32 (last iter only)
    unsigned short* __restrict__ h_bf,         // [1024][256] bf16
    int i_val, int write_f32)
{
    __shared__ float Cs[16][260];
    __shared__ unsigned short hsb[16][264];
    __shared__ float part[16][4][2];
    const int t = threadIdx.x;
    const int w = t >> 6, lane = t & 63;
    const int b = blockIdx.x, jg = blockIdx.y;
    const int j0 = jg * 16;

    // ---- GEMM1: wave w computes C[16 j x 16 d] for nt=w; K=512 ----
    const unsigned short* ab = Af + ((long)(b * 4 + jg) * 16) * 512 + lane * 8;
    const unsigned short* pb = Pf + (long)b * 131072 + w * 512 + lane * 8;
    short8 bfr[16];
#pragma unroll
    for (int tk = 0; tk < 16; ++tk)
        bfr[tk] = *(const short8*)(pb + (long)tk * 8192);
    f32x4 acc = (f32x4){0.f, 0.f, 0.f, 0.f};
#pragma unroll
    for (int tk = 0; tk < 16; ++tk) {
        short8 a = *(const short8*)(ab + (long)tk * 512);
        acc = __builtin_amdgcn_mfma_f32_16x16x32_bf16(a, bfr[tk], acc, 0, 0, 0);
    }
    {
        int n = w * 16 + (lane & 15);
        int m0 = (lane >> 4) * 4;
#pragma unroll
        for (int r = 0; r < 4; ++r) Cs[m0 + r][n] = acc[r];
    }
    __syncthreads();

    // ---- epilogue 1: shrink, +projx, LN over d, gate, relu -> hsb (bf16) ----
    // thread -> (d = t&255, rows rbase..rbase+3), rbase = (w>>2)*4
    const int d = t & 255;
    const int rbase = (w >> 2) * 4;
    const int dseg = w & 3;
    float tv[4];
#pragma unroll
    for (int ri = 0; ri < 4; ++ri) {
        int row = b * 64 + j0 + rbase + ri;
        float lin = Cs[rbase + ri][d];
        float shr = lin - tanhf(lin);
        tv[ri] = projx[row * DD + d] + shr;
    }
#pragma unroll
    for (int ri = 0; ri < 4; ++ri) {
        float s = tv[ri], ss = tv[ri] * tv[ri];
#pragma unroll
        for (int m = 32; m >= 1; m >>= 1) { s += __shfl_xor(s, m); ss += __shfl_xor(ss, m); }
        if (lane == 0) { part[rbase + ri][dseg][0] = s; part[rbase + ri][dseg][1] = ss; }
    }
    __syncthreads();
#pragma unroll
    for (int ri = 0; ri < 4; ++ri) {
        int r = rbase + ri;
        int row = b * 64 + j0 + r;
        float s  = part[r][0][0] + part[r][1][0] + part[r][2][0] + part[r][3][0];
        float ss = part[r][0][1] + part[r][1][1] + part[r][2][1] + part[r][3][1];
        float mean = s * (1.f / 256.f);
        float var  = ss * (1.f / 256.f) - mean * mean;
        float rstd = rsqrtf(var + 1e-5f);
        float nv = (tv[ri] - mean) * rstd;
        float hv = fmaf(shiftb[row * DD + d], nv, scaleb[row * DD + d]);
        hsb[r][d] = f2bf(fmaxf(hv, 0.f));
    }
    __syncthreads();

    // ---- GEMM2: y = h @ W_out; wave w -> nt=w, K=256 (8 tk) ----
    f32x4 acc2 = (f32x4){0.f, 0.f, 0.f, 0.f};
#pragma unroll
    for (int tk = 0; tk < 8; ++tk) {
        short8 a = *(const short8*)(&hsb[lane & 15][tk * 32 + (lane >> 4) * 8]);
        short8 wf = *(const short8*)(Wof + (long)(w * 8 + tk) * 512 + lane * 8);
        acc2 = __builtin_amdgcn_mfma_f32_16x16x32_bf16(a, wf, acc2, 0, 0, 0);
    }
    {
        int n = w * 16 + (lane & 15);
        int m0 = (lane >> 4) * 4;
#pragma unroll
        for (int r = 0; r < 4; ++r) Cs[m0 + r][n] = acc2[r];
    }
    __syncthreads();
    const float bo_d = bout[d];
    const bool maskz = (i_val > lengths[b]);
#pragma unroll
    for (int ri = 0; ri < 4; ++ri) {
        int r = rbase + ri;
        int row = b * 64 + j0 + r;
        float y = tanhf(Cs[r][d] + bo_d);
        float ym = maskz ? 0.f : y;
        h_bf[row * DD + d] = f2bf(ym);
        if (write_f32) h_out[row * DD + d] = ym;
    }
}

// ---------------- final: out[b,d] = sum_i h[b,i,d] * root[b,i] ----------------
__global__ __launch_bounds__(256) void k_final(
    const float* __restrict__ h_buf, const float* __restrict__ root,
    float* __restrict__ out)
{
    const int t = threadIdx.x;
    const int b = blockIdx.x;
    float acc = 0.f;
    for (int i = 0; i < LLEN; ++i)
        acc = fmaf(h_buf[(b * 64 + i) * DD + t], root[b * 64 + i], acc);
    out[b * DD + t] = acc;
}

extern "C" void kernel_launch(void* const* d_in, const int* in_sizes, int n_in,
                              void* d_out, int out_size, void* d_ws, size_t ws_size,
                              hipStream_t stream)
{
    const int*   tokens = (const int*)  d_in[0];
    const float* A      = (const float*)d_in[1];
    const float* root   = (const float*)d_in[2];
    const float* emb    = (const float*)d_in[3];
    const float* Wp     = (const float*)d_in[4];
    const float* bp     = (const float*)d_in[5];
    const float* Wi     = (const float*)d_in[6];
    const float* bi     = (const float*)d_in[7];
    const float* Wo     = (const float*)d_in[8];
    const float* bo     = (const float*)d_in[9];
    float* out = (float*)d_out;

    char* ws = (char*)d_ws;
    int*   lengths = (int*)(ws + 0);
    float* shiftb  = (float*)(ws + 1024);
    float* scaleb  = shiftb + NROWS * DD;
    float* projx   = scaleb + NROWS * DD;
    float* h_out   = projx  + NROWS * DD;                       // 1 MB fp32
    unsigned short* h_bf = (unsigned short*)(h_out + NROWS * DD);  // 512 KB
    unsigned short* Wf   = h_bf + NROWS * DD;                   // 1 MB
    unsigned short* Pf   = Wf + 524288;                         // 4 MB
    unsigned short* Af   = Pf + 2097152;                        // 1 MB
    unsigned short* Wof  = Af + 524288;                         // 128 KB

    hipMemsetAsync(h_bf, 0, (size_t)NROWS * DD * sizeof(unsigned short), stream);
    k_setup<<<1, 64, 0, stream>>>(tokens, lengths);
    k_cvtW<<<256, 256, 0, stream>>>(Wp, Wf);
    k_cvtA<<<256, 256, 0, stream>>>(A, Af);
    k_cvtWo<<<32, 256, 0, stream>>>(Wo, Wof);
    k_inproj<<<128, 256, 0, stream>>>(tokens, emb, Wi, bi, shiftb, scaleb, projx);
    for (int it = 0; it < 64; ++it) {
        int i_val = 64 - it;   // i runs L..1
        k_proj<<<512, 256, 0, stream>>>(h_bf, Wf, bp, Pf);
        k_agg<<<dim3(16, 4), 1024, 0, stream>>>(Af, Pf, projx, shiftb, scaleb,
                                                Wof, bo, lengths, h_out, h_bf,
                                                i_val, (it == 63) ? 1 : 0);
    }
    k_final<<<16, 256, 0, stream>>>(h_out, root, out);
}